// Round 4
// baseline (1619.217 us; speedup 1.0000x reference)
//
#include <hip/hip_runtime.h>
#include <cstdint>
#include <cstddef>

#define BN 256      // batch
#define HN 512      // hidden
#define TSN 128     // src len
#define TTN 32      // tgt len
#define NSL 16      // gate-dim slices
#define SRN 128     // gate rows per slice (4 gates x 32 h-cols)

typedef __fp16 f16;
typedef __fp16 f16x8 __attribute__((ext_vector_type(8)));
typedef float  f32x4 __attribute__((ext_vector_type(4)));
typedef unsigned int u32;
typedef unsigned int u32x2 __attribute__((ext_vector_type(2)));

// ---- workspace layout (bytes) ----
static constexpr size_t WQ_OFF  = 0;                        // 6 matrices, f16, slice-major
static constexpr size_t WQ_MAT  = (size_t)NSL*SRN*HN*2;     // 2 MiB each
static constexpr size_t HS0_OFF = WQ_OFF + 6*WQ_MAT;        // enc L0 h history, slots 0..128
static constexpr size_t HS_SLOT = (size_t)BN*HN*2;          // 256 KiB
static constexpr size_t H1_OFF  = HS0_OFF + 129*HS_SLOT;    // h1 double buffer (slot0 zeroed)
static constexpr size_t H0_OFF  = H1_OFF + 2*HS_SLOT;       // dec h0 double buffer
static constexpr size_t YP_OFF  = H0_OFF + 2*HS_SLOT;       // y partials [B][16] f32
static constexpr size_t BAR_OFF = YP_OFF + (size_t)BN*NSL*4;// flag arrays (device-coherent)
// flags (ints): F0[8][16] @+0, F1[8][16] @+128, FD0[8][16] @+256, FD1[8][16] @+384

__device__ __forceinline__ float sigm(float x){ return 1.f/(1.f+__expf(-x)); }
__device__ __forceinline__ float tanh_(float x){
  float t = __expf(-2.f*fabsf(x));
  float r = (1.f-t)/(1.f+t);
  return x<0.f ? -r : r;
}

//========== device-scope (sc1 = LLC coherence point) asm memory ops ==========
__device__ __forceinline__ f16x8 ldg16_cv(const f16* p){
  f32x4 r;
  asm volatile("global_load_dwordx4 %0, %1, off sc1" : "=v"(r) : "v"(p));
  return __builtin_bit_cast(f16x8, r);
}
__device__ __forceinline__ void stg8_cv(f16* p, u32x2 v){
  asm volatile("global_store_dwordx2 %0, %1, off sc1" :: "v"(p), "v"(v) : "memory");
}
__device__ __forceinline__ void stg4i_cv(int* p, int v){
  asm volatile("global_store_dword %0, %1, off sc1" :: "v"(p), "v"(v) : "memory");
}
__device__ __forceinline__ void stg4f_cv(float* p, float v){
  asm volatile("global_store_dword %0, %1, off sc1" :: "v"(p), "v"(v) : "memory");
}
__device__ __forceinline__ void vmwait(){
  asm volatile("s_waitcnt vmcnt(0)" ::: "memory");
  __builtin_amdgcn_sched_barrier(0);   // rule #18: block reg-only ops from hoisting above the wait
}
// all-wave poll: every wave polls all 16 flags (lane -> flag tid&15); per-wave exit, no barrier.
__device__ __forceinline__ void wait16(const int* f, int target){
  const int* p = f + (threadIdx.x & 15);
  int v;
  for(;;){
    asm volatile("global_load_dword %0, %1, off sc1\n\ts_waitcnt vmcnt(0)"
                 : "=v"(v) : "v"(p) : "memory");
    if (__all(v >= target)) break;
  }
  __builtin_amdgcn_sched_barrier(0);
}
// publish: drain this wave's stores, WG barrier (also orders LDS reuse), then one flag store.
__device__ __forceinline__ void post(int* slot, int v){
  vmwait();
  __syncthreads();
  if (threadIdx.x == 0) stg4i_cv(slot, v);
}

//========== MFMA fragment helpers ==========
// Resident B-frag slice: wave wv covers K = wv*128..+127, all 8 N-tiles. Plain cached loads.
__device__ __forceinline__ void load_bslice(const f16* wsl, int lane, int wv, f16x8 (&bw)[8][4]){
  const int rr = lane & 15;
  const int ko = ((lane>>4)<<3) + wv*128;
  #pragma unroll
  for (int nt=0; nt<8; ++nt){
    const f16* p = wsl + (size_t)(nt*16+rr)*HN + ko;
    #pragma unroll
    for (int kk=0; kk<4; ++kk) bw[nt][kk] = *(const f16x8*)(p + kk*32);
  }
}
// A-frags (recurrent h): device-scope loads, no wait (caller does vmwait once).
template<int MT>
__device__ __forceinline__ void load_a_cv(const f16* ab, int lane, int wv, f16x8 (&A)[MT][4]){
  const int rr = lane & 15;
  const int ko = ((lane>>4)<<3) + wv*128;
  #pragma unroll
  for (int mt=0; mt<MT; ++mt){
    const f16* p = ab + (size_t)(mt*16+rr)*HN + ko;
    #pragma unroll
    for (int kk=0; kk<4; ++kk) A[mt][kk] = ldg16_cv(p + kk*32);
  }
}
// MFMA with register-resident B
__device__ __forceinline__ void mfma_row(const f16x8 (&A)[4], const f16x8 (&bw)[8][4],
                                         f32x4 (&acc)[8]){
  #pragma unroll
  for (int kk=0; kk<4; ++kk)
    #pragma unroll
    for (int nt=0; nt<8; ++nt)
      acc[nt] = __builtin_amdgcn_mfma_f32_16x16x32_f16(A[kk], bw[nt][kk], acc[nt], 0, 0, 0);
}
// MFMA with B streamed from L2-cached weights (no register residency -> no spill)
__device__ __forceinline__ void mfma_stream(const f16* wsl, const f16x8 (&A)[4], int lane, int wv,
                                            f32x4 (&acc)[8]){
  const int rr = lane & 15;
  const int ko = ((lane>>4)<<3) + wv*128;
  #pragma unroll
  for (int nt=0; nt<8; ++nt){
    const f16* p = wsl + (size_t)(nt*16+rr)*HN + ko;
    #pragma unroll
    for (int kk=0; kk<4; ++kk){
      f16x8 b = *(const f16x8*)(p + kk*32);
      acc[nt] = __builtin_amdgcn_mfma_f32_16x16x32_f16(A[kk], b, acc[nt], 0, 0, 0);
    }
  }
}
// C/D frag: col = l&15, row = (l>>4)*4 + i  (learn_hip m89)
__device__ __forceinline__ void wpart1(float (*gS)[32][132], const f32x4 (&acc)[8], int lane, int wv, int mt){
  const int c0 = lane & 15, r0 = (lane>>4)*4;
  #pragma unroll
  for (int nt=0; nt<8; ++nt)
    #pragma unroll
    for (int i=0; i<4; ++i)
      gS[wv][mt*16+r0+i][nt*16+c0] = acc[nt][i];
}
__device__ __forceinline__ float gsum(const float (*gS)[32][132], int row, int r){
  return gS[0][row][r] + gS[1][row][r] + gS[2][row][r] + gS[3][row][r];
}

//========== prologue kernels ==========
__global__ void k_init(uint8_t* ws){
  const int i = blockIdx.x*256 + threadIdx.x;   // 65536 threads
  float* a = (float*)(ws + HS0_OFF);            // hs0 slot0 = zeros (256KB)
  float* b = (float*)(ws + H1_OFF);             // h1 slot0 = zeros
  int*   c = (int*)(ws + BAR_OFF);
  a[i] = 0.f;
  b[i] = 0.f;
  if (i < 2048) c[i] = 0;
}
__global__ void k_wconv(const float* s0, const float* s1, const float* s2,
                        const float* s3, const float* s4, const float* s5, f16* dst){
  const int i = blockIdx.x*256 + threadIdx.x;
  const int k = i & 511, r = (i>>9)&127, j = (i>>16)&15, m = i>>20;
  const float* s = (m==0)?s0:(m==1)?s1:(m==2)?s2:(m==3)?s3:(m==4)?s4:s5;
  const int R = (r>>5)*512 + j*32 + (r&31);
  dst[i] = (f16)s[(size_t)R*HN + k];
}

//========== main persistent kernel ==========
__global__ void __launch_bounds__(256,1) k_main(
    const float* __restrict__ src,   const float* __restrict__ wih0e, const float* __restrict__ b0e,
    const float* __restrict__ b1e,   const float* __restrict__ wih0d, const float* __restrict__ b0d,
    const float* __restrict__ b1d,   const float* __restrict__ projw, const float* __restrict__ projb,
    uint8_t* __restrict__ ws, float* __restrict__ out)
{
  __shared__ float gS[4][32][132];
  __shared__ float srcS[32][TSN];
  __shared__ float wihS[SRN], bS[SRN], pwS[32], yS[32];

  const int wg = blockIdx.x, tid = threadIdx.x;
  const int lane = tid & 63, wv = tid >> 6;
  // XCD grouping: group g's 16 j-WGs (and its partner team at wg+128) land on XCD g under
  // round-robin dispatch (perf heuristic only; correctness is flag-based).
  const int g = wg & 7, j = (wg >> 3) & 15;
  const bool teamA = (wg < 128);   // teamA: enc L0 -> dec cell0 ; teamB: enc L1 -> dec cell1+proj

  const f16* wq = (const f16*)(ws + WQ_OFF);
  f16* hs0 = (f16*)(ws + HS0_OFF);
  f16* h1b = (f16*)(ws + H1_OFF);
  f16* h0b = (f16*)(ws + H0_OFF);
  float* ypb = (float*)(ws + YP_OFF);
  int* F0  = (int*)(ws + BAR_OFF);
  int* F1  = F0 + 128;
  int* FD0 = F0 + 256;
  int* FD1 = F0 + 384;
  int* F0g = F0 + g*16, *F1g = F1 + g*16, *FD0g = FD0 + g*16, *FD1g = FD1 + g*16;

  const int crow = tid >> 3, ckl = (tid & 7)*4;  // cell mapping: 32 rows x (4 cols/thread)
  float creg[4] = {0.f,0.f,0.f,0.f};

  if (teamA){
    //================= encoder layer 0 =================
    f16x8 bw[8][4];
    load_bslice(wq + (size_t)(0*NSL + j)*SRN*HN, lane, wv, bw);    // W_hh0 enc, resident
    for (int i=tid; i<SRN; i+=256){
      int R = (i>>5)*512 + j*32 + (i&31);
      wihS[i] = wih0e[R]; bS[i] = b0e[R];
    }
    for (int i=tid; i<32*TSN; i+=256)
      srcS[i>>7][i&127] = src[(size_t)(g*32 + (i>>7))*TSN + (i&127)];
    __syncthreads();

    for (int t=0; t<TSN; ++t){
      wait16(F0g, t);
      f16x8 A[2][4];
      load_a_cv<2>(hs0 + (size_t)t*BN*HN + (size_t)g*32*HN, lane, wv, A);
      vmwait();
      f32x4 acc[2][8];
      #pragma unroll
      for (int mt=0; mt<2; ++mt)
        #pragma unroll
        for (int nt=0; nt<8; ++nt) acc[mt][nt] = f32x4{0.f,0.f,0.f,0.f};
      mfma_row(A[0], bw, acc[0]);
      mfma_row(A[1], bw, acc[1]);
      wpart1(gS, acc[0], lane, wv, 0);
      wpart1(gS, acc[1], lane, wv, 1);
      __syncthreads();

      const float xs = srcS[crow][t];
      f16 hv[4];
      #pragma unroll
      for (int q=0; q<4; ++q){
        const int kl = ckl + q;
        float gi = gsum(gS, crow, kl)    + xs*wihS[kl]    + bS[kl];
        float gf = gsum(gS, crow, 32+kl) + xs*wihS[32+kl] + bS[32+kl];
        float gg = gsum(gS, crow, 64+kl) + xs*wihS[64+kl] + bS[64+kl];
        float go = gsum(gS, crow, 96+kl) + xs*wihS[96+kl] + bS[96+kl];
        float cc = sigm(gf)*creg[q] + sigm(gi)*tanh_(gg);
        creg[q] = cc;
        hv[q] = (f16)(sigm(go)*tanh_(cc));
      }
      union { f16 h4[4]; u32x2 u; } pk;
      #pragma unroll
      for (int q=0; q<4; ++q) pk.h4[q] = hv[q];
      stg8_cv(hs0 + (size_t)(t+1)*BN*HN + (size_t)(g*32+crow)*HN + j*32 + ckl, pk.u);
      post(F0g + j, t+1);
    }

    //================= decoder cell0 =================
    load_bslice(wq + (size_t)(3*NSL + j)*SRN*HN, lane, wv, bw);   // dec W_hh0, resident
    for (int i=tid; i<SRN; i+=256){
      int R = (i>>5)*512 + j*32 + (i&31);
      wihS[i] = wih0d[R]; bS[i] = b0d[R];
    }
    const float pb = projb[0];
    __syncthreads();   // creg already holds c0 (same thread mapping)

    for (int t=0; t<TTN; ++t){
      // GEMM first (y-independent)
      if (t == 0) wait16(F0g, TSN); else wait16(FD0g, t);
      f16x8 A[2][4];
      const f16* hb = (t==0) ? (hs0 + (size_t)TSN*BN*HN + (size_t)g*32*HN)
                             : (h0b + (size_t)(t&1)*HS_SLOT/2 + (size_t)g*32*HN);
      load_a_cv<2>(hb, lane, wv, A);
      vmwait();
      f32x4 acc[2][8];
      #pragma unroll
      for (int mt=0; mt<2; ++mt)
        #pragma unroll
        for (int nt=0; nt<8; ++nt) acc[mt][nt] = f32x4{0.f,0.f,0.f,0.f};
      mfma_row(A[0], bw, acc[0]);
      mfma_row(A[1], bw, acc[1]);
      wpart1(gS, acc[0], lane, wv, 0);
      wpart1(gS, acc[1], lane, wv, 1);
      __syncthreads();

      // y feedback
      if (t == 0){
        if (tid < 32) yS[tid] = src[(size_t)(g*32+tid)*TSN + (TSN-1)];
      } else {
        wait16(FD1g, t);
        if (tid < 32){
          const float* pr = ypb + (size_t)(g*32+tid)*NSL;
          f32x4 r0,r1,r2,r3;
          asm volatile("global_load_dwordx4 %0, %4, off sc1\n\t"
                       "global_load_dwordx4 %1, %5, off sc1\n\t"
                       "global_load_dwordx4 %2, %6, off sc1\n\t"
                       "global_load_dwordx4 %3, %7, off sc1\n\t"
                       "s_waitcnt vmcnt(0)"
                       : "=&v"(r0),"=&v"(r1),"=&v"(r2),"=&v"(r3)
                       : "v"(pr),"v"(pr+4),"v"(pr+8),"v"(pr+12) : "memory");
          float y = pb + r0[0]+r0[1]+r0[2]+r0[3] + r1[0]+r1[1]+r1[2]+r1[3]
                       + r2[0]+r2[1]+r2[2]+r2[3] + r3[0]+r3[1]+r3[2]+r3[3];
          yS[tid] = y;
          if (j == 0) out[(size_t)(g*32+tid)*TTN + (t-1)] = y;
        }
      }
      __syncthreads();

      const float yv = yS[crow];
      f16 hv[4];
      #pragma unroll
      for (int q=0; q<4; ++q){
        const int kl = ckl + q;
        float gi = gsum(gS, crow, kl)    + yv*wihS[kl]    + bS[kl];
        float gf = gsum(gS, crow, 32+kl) + yv*wihS[32+kl] + bS[32+kl];
        float gg = gsum(gS, crow, 64+kl) + yv*wihS[64+kl] + bS[64+kl];
        float go = gsum(gS, crow, 96+kl) + yv*wihS[96+kl] + bS[96+kl];
        float cc = sigm(gf)*creg[q] + sigm(gi)*tanh_(gg);
        creg[q] = cc;
        hv[q] = (f16)(sigm(go)*tanh_(cc));
      }
      union { f16 h4[4]; u32x2 u; } pk;
      #pragma unroll
      for (int q=0; q<4; ++q) pk.h4[q] = hv[q];
      stg8_cv(h0b + (size_t)((t+1)&1)*HS_SLOT/2 + (size_t)(g*32+crow)*HN + j*32 + ckl, pk.u);
      post(FD0g + j, t+1);
    }

    // epilogue: y for t = 31
    if (j == 0){
      wait16(FD1g, TTN);
      if (tid < 32){
        const float* pr = ypb + (size_t)(g*32+tid)*NSL;
        f32x4 r0,r1,r2,r3;
        asm volatile("global_load_dwordx4 %0, %4, off sc1\n\t"
                     "global_load_dwordx4 %1, %5, off sc1\n\t"
                     "global_load_dwordx4 %2, %6, off sc1\n\t"
                     "global_load_dwordx4 %3, %7, off sc1\n\t"
                     "s_waitcnt vmcnt(0)"
                     : "=&v"(r0),"=&v"(r1),"=&v"(r2),"=&v"(r3)
                     : "v"(pr),"v"(pr+4),"v"(pr+8),"v"(pr+12) : "memory");
        float y = projb[0] + r0[0]+r0[1]+r0[2]+r0[3] + r1[0]+r1[1]+r1[2]+r1[3]
                           + r2[0]+r2[1]+r2[2]+r2[3] + r3[0]+r3[1]+r3[2]+r3[3];
        out[(size_t)(g*32+tid)*TTN + (TTN-1)] = y;
      }
    }
  } else {
    //================= encoder layer 1 =================
    f16x8 bwh[8][4];
    load_bslice(wq + (size_t)(2*NSL + j)*SRN*HN, lane, wv, bwh);   // enc W_hh1, resident
    const f16* wih1p = wq + (size_t)(1*NSL + j)*SRN*HN;            // enc W_ih1, streamed (L2-hit)
    for (int i=tid; i<SRN; i+=256){
      int R = (i>>5)*512 + j*32 + (i&31);
      bS[i] = b1e[R];
    }
    __syncthreads();

    for (int t=0; t<TSN; ++t){
      wait16(F1g, t);
      f16x8 A[2][4];
      load_a_cv<2>(h1b + (size_t)(t&1)*HS_SLOT/2 + (size_t)g*32*HN, lane, wv, A);
      vmwait();
      f32x4 acc[2][8];
      #pragma unroll
      for (int mt=0; mt<2; ++mt)
        #pragma unroll
        for (int nt=0; nt<8; ++nt) acc[mt][nt] = f32x4{0.f,0.f,0.f,0.f};
      mfma_row(A[0], bwh, acc[0]);
      mfma_row(A[1], bwh, acc[1]);
      wait16(F0g, t+1);
      f16x8 A2[2][4];
      load_a_cv<2>(hs0 + (size_t)(t+1)*BN*HN + (size_t)g*32*HN, lane, wv, A2);
      vmwait();
      mfma_stream(wih1p, A2[0], lane, wv, acc[0]);
      mfma_stream(wih1p, A2[1], lane, wv, acc[1]);
      wpart1(gS, acc[0], lane, wv, 0);
      wpart1(gS, acc[1], lane, wv, 1);
      __syncthreads();

      f16 hv[4];
      #pragma unroll
      for (int q=0; q<4; ++q){
        const int kl = ckl + q;
        float gi = gsum(gS, crow, kl)    + bS[kl];
        float gf = gsum(gS, crow, 32+kl) + bS[32+kl];
        float gg = gsum(gS, crow, 64+kl) + bS[64+kl];
        float go = gsum(gS, crow, 96+kl) + bS[96+kl];
        float cc = sigm(gf)*creg[q] + sigm(gi)*tanh_(gg);
        creg[q] = cc;
        hv[q] = (f16)(sigm(go)*tanh_(cc));
      }
      union { f16 h4[4]; u32x2 u; } pk;
      #pragma unroll
      for (int q=0; q<4; ++q) pk.h4[q] = hv[q];
      stg8_cv(h1b + (size_t)((t+1)&1)*HS_SLOT/2 + (size_t)(g*32+crow)*HN + j*32 + ckl, pk.u);
      post(F1g + j, t+1);
    }

    //================= decoder cell1 + proj =================
    f16x8 bwb[8][4];
    load_bslice(wq + (size_t)(5*NSL + j)*SRN*HN, lane, wv, bwb);   // dec W_hh1, resident
    const f16* wih1d = wq + (size_t)(4*NSL + j)*SRN*HN;            // dec W_ih1, streamed
    for (int i=tid; i<SRN; i+=256){
      int R = (i>>5)*512 + j*32 + (i&31);
      bS[i] = b1d[R];
    }
    if (tid < 32) pwS[tid] = projw[j*32 + tid];
    __syncthreads();   // creg already holds c1

    for (int t=0; t<TTN; ++t){
      if (t == 0) wait16(F1g, TSN); else wait16(FD1g, t);
      f16x8 A[2][4];
      load_a_cv<2>(h1b + (size_t)(t&1)*HS_SLOT/2 + (size_t)g*32*HN, lane, wv, A);
      vmwait();
      f32x4 acc[2][8];
      #pragma unroll
      for (int mt=0; mt<2; ++mt)
        #pragma unroll
        for (int nt=0; nt<8; ++nt) acc[mt][nt] = f32x4{0.f,0.f,0.f,0.f};
      mfma_row(A[0], bwb, acc[0]);                 // W_hh1 @ h1_t
      mfma_row(A[1], bwb, acc[1]);
      wait16(FD0g, t+1);
      f16x8 A2[2][4];
      load_a_cv<2>(h0b + (size_t)((t+1)&1)*HS_SLOT/2 + (size_t)g*32*HN, lane, wv, A2);
      vmwait();
      mfma_stream(wih1d, A2[0], lane, wv, acc[0]); // + W_ih1 @ h0_{t+1}
      mfma_stream(wih1d, A2[1], lane, wv, acc[1]);
      wpart1(gS, acc[0], lane, wv, 0);
      wpart1(gS, acc[1], lane, wv, 1);
      __syncthreads();

      f16 hv[4];
      float hvf[4];
      #pragma unroll
      for (int q=0; q<4; ++q){
        const int kl = ckl + q;
        float gi = gsum(gS, crow, kl)    + bS[kl];
        float gf = gsum(gS, crow, 32+kl) + bS[32+kl];
        float gg = gsum(gS, crow, 64+kl) + bS[64+kl];
        float go = gsum(gS, crow, 96+kl) + bS[96+kl];
        float cc = sigm(gf)*creg[q] + sigm(gi)*tanh_(gg);
        creg[q] = cc;
        hvf[q] = sigm(go)*tanh_(cc);
        hv[q] = (f16)hvf[q];
      }
      union { f16 h4[4]; u32x2 u; } pk;
      #pragma unroll
      for (int q=0; q<4; ++q) pk.h4[q] = hv[q];
      stg8_cv(h1b + (size_t)((t+1)&1)*HS_SLOT/2 + (size_t)(g*32+crow)*HN + j*32 + ckl, pk.u);

      float pp = hvf[0]*pwS[ckl] + hvf[1]*pwS[ckl+1] + hvf[2]*pwS[ckl+2] + hvf[3]*pwS[ckl+3];
      pp += __shfl_xor(pp, 1);
      pp += __shfl_xor(pp, 2);
      pp += __shfl_xor(pp, 4);
      if ((tid & 7) == 0) stg4f_cv(ypb + (size_t)(g*32+crow)*NSL + j, pp);
      post(FD1g + j, t+1);
    }
  }
}

extern "C" void kernel_launch(void* const* d_in, const int* in_sizes, int n_in,
                              void* d_out, int out_size, void* d_ws, size_t ws_size,
                              hipStream_t stream)
{
  (void)in_sizes; (void)n_in; (void)out_size; (void)ws_size;
  const float* src   = (const float*)d_in[0];
  const float* wih0e = (const float*)d_in[1];
  const float* hh0e  = (const float*)d_in[2];
  const float* b0e   = (const float*)d_in[3];
  const float* ih1e  = (const float*)d_in[4];
  const float* hh1e  = (const float*)d_in[5];
  const float* b1e   = (const float*)d_in[6];
  const float* wih0d = (const float*)d_in[7];
  const float* hh0d  = (const float*)d_in[8];
  const float* b0d   = (const float*)d_in[9];
  const float* ih1d  = (const float*)d_in[10];
  const float* hh1d  = (const float*)d_in[11];
  const float* b1d   = (const float*)d_in[12];
  const float* projw = (const float*)d_in[13];
  const float* projb = (const float*)d_in[14];
  uint8_t* ws = (uint8_t*)d_ws;
  float* out = (float*)d_out;

  k_init<<<dim3(256), dim3(256), 0, stream>>>(ws);
  k_wconv<<<dim3(6*NSL*SRN*HN/256), dim3(256), 0, stream>>>(hh0e, ih1e, hh1e, hh0d, ih1d, hh1d,
                                                            (f16*)(ws + WQ_OFF));
  k_main<<<dim3(256), dim3(256), 0, stream>>>(src, wih0e, b0e, b1e, wih0d, b0d, b1d,
                                              projw, projb, ws, out);
}

// Round 6
// 1300.231 us; speedup vs baseline: 1.2453x; 1.2453x over previous
//
#include <hip/hip_runtime.h>
#include <cstdint>
#include <cstddef>

#define BN 256      // batch
#define HN 512      // hidden
#define TSN 128     // src len
#define TTN 32      // tgt len
#define NSL 16      // gate-dim slices
#define SRN 128     // gate rows per slice (4 gates x 32 h-cols)

typedef __fp16 f16;
typedef __fp16 f16x8 __attribute__((ext_vector_type(8)));
typedef float  f32x4 __attribute__((ext_vector_type(4)));
typedef float  f32x2 __attribute__((ext_vector_type(2)));
typedef unsigned int u32;
typedef unsigned int u32x2 __attribute__((ext_vector_type(2)));

// ---- workspace layout (bytes) ----
static constexpr size_t WQ_OFF  = 0;                        // 6 matrices, f16, slice-major
static constexpr size_t WQ_MAT  = (size_t)NSL*SRN*HN*2;     // 2 MiB each
static constexpr size_t HS0_OFF = WQ_OFF + 6*WQ_MAT;        // enc L0 h history, slots 0..128 (no ring, no WAR)
static constexpr size_t HS_SLOT = (size_t)BN*HN*2;          // 256 KiB
static constexpr size_t H1_OFF  = HS0_OFF + 129*HS_SLOT;    // h1 double buffer (slot0 zeroed)
static constexpr size_t H0_OFF  = H1_OFF + 2*HS_SLOT;       // dec h0 double buffer
static constexpr size_t YP_OFF  = H0_OFF + 2*HS_SLOT;       // y partials [B][16] f32
static constexpr size_t BAR_OFF = YP_OFF + (size_t)BN*NSL*4;// per-wave flags
// flags (ints): F0[8][64] @+0, F1[8][64] @+512, FD0[8][64] @+1024, FD1[8][64] @+1536
// flag slot within group: j*4 + wave

__device__ __forceinline__ float sigm(float x){ return 1.f/(1.f+__expf(-x)); }
__device__ __forceinline__ float tanh_(float x){
  float t = __expf(-2.f*fabsf(x));
  float r = (1.f-t)/(1.f+t);
  return x<0.f ? -r : r;
}

//========== device-scope (sc1, LLC coherence point) asm memory ops ==========
__device__ __forceinline__ f16x8 ldg16_cv(const f16* p){
  f32x4 r;
  asm volatile("global_load_dwordx4 %0, %1, off sc1" : "=v"(r) : "v"(p));
  return __builtin_bit_cast(f16x8, r);
}
__device__ __forceinline__ f32x2 ldg8f_cv(const float* p){
  f32x2 r;
  asm volatile("global_load_dwordx2 %0, %1, off sc1" : "=v"(r) : "v"(p));
  return r;
}
__device__ __forceinline__ void stg8_cv(f16* p, u32x2 v){
  asm volatile("global_store_dwordx2 %0, %1, off sc1" :: "v"(p), "v"(v) : "memory");
}
__device__ __forceinline__ void stg4f_cv(float* p, float v){
  asm volatile("global_store_dword %0, %1, off sc1" :: "v"(p), "v"(v) : "memory");
}
__device__ __forceinline__ void vmwait(){
  asm volatile("s_waitcnt vmcnt(0)" ::: "memory");
  __builtin_amdgcn_sched_barrier(0);   // rule #18: keep reg-only consumers below the wait
}
// K-structured wait: wave wv's A-fragment spans K cols written by producer WGs j in
// [4wv, 4wv+4), all 4 of their waves -> 16 flags, lane-parallel, barrier-free.
__device__ __forceinline__ void wait_k(const int* fb, int wv, int target){
  const int l = threadIdx.x & 63;
  const int* p = fb + (((wv<<2) | ((l>>2)&3))<<2) + (l&3);
  int v;
  do {
    asm volatile("global_load_dword %0, %1, off sc1\n\ts_waitcnt vmcnt(0)"
                 : "=v"(v) : "v"(p) : "memory");
  } while (!__all(v >= target));
  __builtin_amdgcn_sched_barrier(0);
}
// row-structured wait (yp): wave wv consumes rows [8wv,8wv+8) from all 16 j's wave wv.
__device__ __forceinline__ void wait_row(const int* fb, int wv, int target){
  const int l = threadIdx.x & 63;
  const int* p = fb + ((l&15)<<2) + wv;
  int v;
  do {
    asm volatile("global_load_dword %0, %1, off sc1\n\ts_waitcnt vmcnt(0)"
                 : "=v"(v) : "v"(p) : "memory");
  } while (!__all(v >= target));
  __builtin_amdgcn_sched_barrier(0);
}
// per-wave publish: drain THIS wave's stores, lane0 posts the wave's flag. No barrier.
__device__ __forceinline__ void post_wave(int* slot, int v){
  asm volatile("s_waitcnt vmcnt(0)" ::: "memory");
  __builtin_amdgcn_sched_barrier(0);
  if ((threadIdx.x & 63) == 0)
    asm volatile("global_store_dword %0, %1, off sc1" :: "v"(slot), "v"(v) : "memory");
}
__device__ __forceinline__ void post_wave2(int* sa, int va, int* sb, int vb){
  asm volatile("s_waitcnt vmcnt(0)" ::: "memory");
  __builtin_amdgcn_sched_barrier(0);
  if ((threadIdx.x & 63) == 0){
    asm volatile("global_store_dword %0, %1, off sc1" :: "v"(sa), "v"(va) : "memory");
    asm volatile("global_store_dword %0, %1, off sc1" :: "v"(sb), "v"(vb) : "memory");
  }
}

//========== MFMA fragment helpers ==========
// Resident B-frag slice: wave wv covers K = wv*128..+127, all 8 N-tiles (plain cached loads).
__device__ __forceinline__ void load_bslice(const f16* wsl, int lane, int wv, f16x8 (&bw)[8][4]){
  const int rr = lane & 15;
  const int ko = ((lane>>4)<<3) + wv*128;
  #pragma unroll
  for (int nt=0; nt<8; ++nt){
    const f16* p = wsl + (size_t)(nt*16+rr)*HN + ko;
    #pragma unroll
    for (int kk=0; kk<4; ++kk) bw[nt][kk] = *(const f16x8*)(p + kk*32);
  }
}
// A-frags (recurrent h): device-scope loads, caller does vmwait once.
template<int MT>
__device__ __forceinline__ void load_a_cv(const f16* ab, int lane, int wv, f16x8 (&A)[MT][4]){
  const int rr = lane & 15;
  const int ko = ((lane>>4)<<3) + wv*128;
  #pragma unroll
  for (int mt=0; mt<MT; ++mt){
    const f16* p = ab + (size_t)(mt*16+rr)*HN + ko;
    #pragma unroll
    for (int kk=0; kk<4; ++kk) A[mt][kk] = ldg16_cv(p + kk*32);
  }
}
__device__ __forceinline__ void mfma_row(const f16x8 (&A)[4], const f16x8 (&bw)[8][4],
                                         f32x4 (&acc)[8]){
  #pragma unroll
  for (int kk=0; kk<4; ++kk)
    #pragma unroll
    for (int nt=0; nt<8; ++nt)
      acc[nt] = __builtin_amdgcn_mfma_f32_16x16x32_f16(A[kk], bw[nt][kk], acc[nt], 0, 0, 0);
}
// C/D frag: col = l&15, row = (l>>4)*4 + i  (learn_hip m89)
__device__ __forceinline__ void wpart1(float (*gS)[32][132], const f32x4 (&acc)[8], int lane, int wv, int mt){
  const int c0 = lane & 15, r0 = (lane>>4)*4;
  #pragma unroll
  for (int nt=0; nt<8; ++nt)
    #pragma unroll
    for (int i=0; i<4; ++i)
      gS[wv][mt*16+r0+i][nt*16+c0] = acc[nt][i];
}
__device__ __forceinline__ float gsum(const float (*gS)[32][132], int row, int r){
  return gS[0][row][r] + gS[1][row][r] + gS[2][row][r] + gS[3][row][r];
}

//========== prologue kernels ==========
__global__ void k_init(uint8_t* ws){
  const int i = blockIdx.x*256 + threadIdx.x;   // 65536 threads
  float* a = (float*)(ws + HS0_OFF);            // hs0 slot0 = zeros (256KB)
  float* b = (float*)(ws + H1_OFF);             // h1 slot0 = zeros
  int*   c = (int*)(ws + BAR_OFF);
  a[i] = 0.f;
  b[i] = 0.f;
  if (i < 2048) c[i] = 0;
}
__global__ void k_wconv(const float* s0, const float* s1, const float* s2,
                        const float* s3, const float* s4, const float* s5, f16* dst){
  const int i = blockIdx.x*256 + threadIdx.x;
  const int k = i & 511, r = (i>>9)&127, j = (i>>16)&15, m = i>>20;
  const float* s = (m==0)?s0:(m==1)?s1:(m==2)?s2:(m==3)?s3:(m==4)?s4:s5;
  const int R = (r>>5)*512 + j*32 + (r&31);
  dst[i] = (f16)s[(size_t)R*HN + k];
}

//========== main persistent kernel ==========
__global__ void __launch_bounds__(256,1) k_main(
    const float* __restrict__ src,   const float* __restrict__ wih0e, const float* __restrict__ b0e,
    const float* __restrict__ b1e,   const float* __restrict__ wih0d, const float* __restrict__ b0d,
    const float* __restrict__ b1d,   const float* __restrict__ projw, const float* __restrict__ projb,
    uint8_t* __restrict__ ws, float* __restrict__ out)
{
  __shared__ float gS[4][32][132];
  __shared__ float srcS[32][TSN];
  __shared__ float wihS[SRN], bS[SRN], pwS[32], yS[32];

  const int wg = blockIdx.x, tid = threadIdx.x;
  const int lane = tid & 63, wv = tid >> 6;
  const int g = (wg >> 4) & 7, j = wg & 15;     // round-2 proven mapping
  const bool teamA = (wg < 128);   // teamA: enc L0 -> dec cell0 ; teamB: enc L1 -> dec cell1+proj

  const f16* wq = (const f16*)(ws + WQ_OFF);
  f16* hs0 = (f16*)(ws + HS0_OFF);
  f16* h1b = (f16*)(ws + H1_OFF);
  f16* h0b = (f16*)(ws + H0_OFF);
  float* ypb = (float*)(ws + YP_OFF);
  int* F0  = (int*)(ws + BAR_OFF);
  int* F1  = F0 + 512;
  int* FD0 = F0 + 1024;
  int* FD1 = F0 + 1536;
  int* F0g = F0 + g*64, *F1g = F1 + g*64, *FD0g = FD0 + g*64, *FD1g = FD1 + g*64;
  const int fslot = j*4 + wv;

  const int crow = tid >> 3, ckl = (tid & 7)*4;  // cell mapping: 32 rows x (4 cols/thread)
  float creg[4] = {0.f,0.f,0.f,0.f};

  if (teamA){
    //================= encoder layer 0 =================
    f16x8 bw[8][4];
    load_bslice(wq + (size_t)(0*NSL + j)*SRN*HN, lane, wv, bw);    // enc W_hh0, resident
    for (int i=tid; i<SRN; i+=256){
      int R = (i>>5)*512 + j*32 + (i&31);
      wihS[i] = wih0e[R]; bS[i] = b0e[R];
    }
    for (int i=tid; i<32*TSN; i+=256)
      srcS[i>>7][i&127] = src[(size_t)(g*32 + (i>>7))*TSN + (i&127)];
    __syncthreads();

    for (int t=0; t<TSN; ++t){
      wait_k(F0g, wv, t);
      f16x8 A[2][4];
      load_a_cv<2>(hs0 + (size_t)t*BN*HN + (size_t)g*32*HN, lane, wv, A);
      vmwait();
      f32x4 acc[2][8];
      #pragma unroll
      for (int mt=0; mt<2; ++mt)
        #pragma unroll
        for (int nt=0; nt<8; ++nt) acc[mt][nt] = f32x4{0.f,0.f,0.f,0.f};
      mfma_row(A[0], bw, acc[0]);
      mfma_row(A[1], bw, acc[1]);
      wpart1(gS, acc[0], lane, wv, 0);
      wpart1(gS, acc[1], lane, wv, 1);
      __syncthreads();                                   // #1: partials visible

      const float xs = srcS[crow][t];
      f16 hv[4];
      #pragma unroll
      for (int q=0; q<4; ++q){
        const int kl = ckl + q;
        float gi = gsum(gS, crow, kl)    + xs*wihS[kl]    + bS[kl];
        float gf = gsum(gS, crow, 32+kl) + xs*wihS[32+kl] + bS[32+kl];
        float gg = gsum(gS, crow, 64+kl) + xs*wihS[64+kl] + bS[64+kl];
        float go = gsum(gS, crow, 96+kl) + xs*wihS[96+kl] + bS[96+kl];
        float cc = sigm(gf)*creg[q] + sigm(gi)*tanh_(gg);
        creg[q] = cc;
        hv[q] = (f16)(sigm(go)*tanh_(cc));
      }
      __syncthreads();                                   // #2: gS reads done (next wpart safe)

      union { f16 h4[4]; u32x2 u; } pk;
      #pragma unroll
      for (int q=0; q<4; ++q) pk.h4[q] = hv[q];
      stg8_cv(hs0 + (size_t)(t+1)*BN*HN + (size_t)(g*32+crow)*HN + j*32 + ckl, pk.u);
      post_wave(F0g + fslot, t+1);
    }

    //================= decoder cell0 =================
    load_bslice(wq + (size_t)(3*NSL + j)*SRN*HN, lane, wv, bw);   // dec W_hh0, resident
    for (int i=tid; i<SRN; i+=256){
      int R = (i>>5)*512 + j*32 + (i&31);
      wihS[i] = wih0d[R]; bS[i] = b0d[R];
    }
    const float pb = projb[0];
    __syncthreads();   // creg already holds c0 (same thread mapping)

    for (int t=0; t<TTN; ++t){
      // GEMM first (y-independent)
      f16x8 A[2][4];
      const f16* hb;
      if (t == 0){ wait_k(F0g, wv, TSN); hb = hs0 + (size_t)TSN*BN*HN + (size_t)g*32*HN; }
      else       { wait_k(FD0g, wv, t);  hb = h0b + (size_t)(t&1)*HS_SLOT/2 + (size_t)g*32*HN; }
      load_a_cv<2>(hb, lane, wv, A);
      vmwait();
      f32x4 acc[2][8];
      #pragma unroll
      for (int mt=0; mt<2; ++mt)
        #pragma unroll
        for (int nt=0; nt<8; ++nt) acc[mt][nt] = f32x4{0.f,0.f,0.f,0.f};
      mfma_row(A[0], bw, acc[0]);
      mfma_row(A[1], bw, acc[1]);
      wpart1(gS, acc[0], lane, wv, 0);
      wpart1(gS, acc[1], lane, wv, 1);
      __syncthreads();                                   // #1

      // y feedback
      if (t == 0){
        if (tid < 32) yS[tid] = src[(size_t)(g*32+tid)*TSN + (TSN-1)];
      } else {
        wait_row(FD1g, wv, t);
        f32x2 v2 = ldg8f_cv(ypb + (size_t)(g*32+crow)*NSL + (tid&7)*2);
        vmwait();
        float pp = v2[0] + v2[1];
        pp += __shfl_xor(pp, 1);
        pp += __shfl_xor(pp, 2);
        pp += __shfl_xor(pp, 4);
        if ((tid & 7) == 0){
          float y = pb + pp;
          yS[crow] = y;
          if (j == 0) out[(size_t)(g*32+crow)*TTN + (t-1)] = y;
        }
      }
      __syncthreads();                                   // #1b: yS visible

      const float yv = yS[crow];
      f16 hv[4];
      #pragma unroll
      for (int q=0; q<4; ++q){
        const int kl = ckl + q;
        float gi = gsum(gS, crow, kl)    + yv*wihS[kl]    + bS[kl];
        float gf = gsum(gS, crow, 32+kl) + yv*wihS[32+kl] + bS[32+kl];
        float gg = gsum(gS, crow, 64+kl) + yv*wihS[64+kl] + bS[64+kl];
        float go = gsum(gS, crow, 96+kl) + yv*wihS[96+kl] + bS[96+kl];
        float cc = sigm(gf)*creg[q] + sigm(gi)*tanh_(gg);
        creg[q] = cc;
        hv[q] = (f16)(sigm(go)*tanh_(cc));
      }
      __syncthreads();                                   // #2

      union { f16 h4[4]; u32x2 u; } pk;
      #pragma unroll
      for (int q=0; q<4; ++q) pk.h4[q] = hv[q];
      stg8_cv(h0b + (size_t)((t+1)&1)*HS_SLOT/2 + (size_t)(g*32+crow)*HN + j*32 + ckl, pk.u);
      post_wave(FD0g + fslot, t+1);
    }

    // epilogue: y for t = 31
    if (j == 0){
      wait_row(FD1g, wv, TTN);
      f32x2 v2 = ldg8f_cv(ypb + (size_t)(g*32+crow)*NSL + (tid&7)*2);
      vmwait();
      float pp = v2[0] + v2[1];
      pp += __shfl_xor(pp, 1);
      pp += __shfl_xor(pp, 2);
      pp += __shfl_xor(pp, 4);
      if ((tid & 7) == 0) out[(size_t)(g*32+crow)*TTN + (TTN-1)] = pb + pp;
    }
  } else {
    //================= encoder layer 1 =================
    f16x8 bwi[8][4], bwh[8][4];
    load_bslice(wq + (size_t)(1*NSL + j)*SRN*HN, lane, wv, bwi);   // enc W_ih1
    load_bslice(wq + (size_t)(2*NSL + j)*SRN*HN, lane, wv, bwh);   // enc W_hh1
    for (int i=tid; i<SRN; i+=256){
      int R = (i>>5)*512 + j*32 + (i&31);
      bS[i] = b1e[R];
    }
    __syncthreads();

    for (int t=0; t<TSN; ++t){
      wait_k(F1g, wv, t);
      f16x8 A[2][4];
      load_a_cv<2>(h1b + (size_t)(t&1)*HS_SLOT/2 + (size_t)g*32*HN, lane, wv, A);
      vmwait();
      f32x4 acc[2][8];
      #pragma unroll
      for (int mt=0; mt<2; ++mt)
        #pragma unroll
        for (int nt=0; nt<8; ++nt) acc[mt][nt] = f32x4{0.f,0.f,0.f,0.f};
      mfma_row(A[0], bwh, acc[0]);
      mfma_row(A[1], bwh, acc[1]);
      wait_k(F0g, wv, t+1);
      f16x8 A2[2][4];
      load_a_cv<2>(hs0 + (size_t)(t+1)*BN*HN + (size_t)g*32*HN, lane, wv, A2);
      vmwait();
      mfma_row(A2[0], bwi, acc[0]);
      mfma_row(A2[1], bwi, acc[1]);
      wpart1(gS, acc[0], lane, wv, 0);
      wpart1(gS, acc[1], lane, wv, 1);
      __syncthreads();                                   // #1

      f16 hv[4];
      #pragma unroll
      for (int q=0; q<4; ++q){
        const int kl = ckl + q;
        float gi = gsum(gS, crow, kl)    + bS[kl];
        float gf = gsum(gS, crow, 32+kl) + bS[32+kl];
        float gg = gsum(gS, crow, 64+kl) + bS[64+kl];
        float go = gsum(gS, crow, 96+kl) + bS[96+kl];
        float cc = sigm(gf)*creg[q] + sigm(gi)*tanh_(gg);
        creg[q] = cc;
        hv[q] = (f16)(sigm(go)*tanh_(cc));
      }
      __syncthreads();                                   // #2

      union { f16 h4[4]; u32x2 u; } pk;
      #pragma unroll
      for (int q=0; q<4; ++q) pk.h4[q] = hv[q];
      stg8_cv(h1b + (size_t)((t+1)&1)*HS_SLOT/2 + (size_t)(g*32+crow)*HN + j*32 + ckl, pk.u);
      post_wave(F1g + fslot, t+1);
    }

    //================= decoder cell1 + proj =================
    load_bslice(wq + (size_t)(4*NSL + j)*SRN*HN, lane, wv, bwi);   // dec W_ih1
    load_bslice(wq + (size_t)(5*NSL + j)*SRN*HN, lane, wv, bwh);   // dec W_hh1
    for (int i=tid; i<SRN; i+=256){
      int R = (i>>5)*512 + j*32 + (i&31);
      bS[i] = b1d[R];
    }
    if (tid < 32) pwS[tid] = projw[j*32 + tid];
    __syncthreads();   // creg already holds c1

    for (int t=0; t<TTN; ++t){
      wait_k(F1g, wv, TSN + t);
      f16x8 A[2][4];
      load_a_cv<2>(h1b + (size_t)(t&1)*HS_SLOT/2 + (size_t)g*32*HN, lane, wv, A);
      vmwait();
      f32x4 acc[2][8];
      #pragma unroll
      for (int mt=0; mt<2; ++mt)
        #pragma unroll
        for (int nt=0; nt<8; ++nt) acc[mt][nt] = f32x4{0.f,0.f,0.f,0.f};
      mfma_row(A[0], bwh, acc[0]);                 // W_hh1 @ h1_t
      mfma_row(A[1], bwh, acc[1]);
      wait_k(FD0g, wv, t+1);
      f16x8 A2[2][4];
      load_a_cv<2>(h0b + (size_t)((t+1)&1)*HS_SLOT/2 + (size_t)g*32*HN, lane, wv, A2);
      vmwait();
      mfma_row(A2[0], bwi, acc[0]);                // + W_ih1 @ h0_{t+1}
      mfma_row(A2[1], bwi, acc[1]);
      wpart1(gS, acc[0], lane, wv, 0);
      wpart1(gS, acc[1], lane, wv, 1);
      __syncthreads();                                   // #1

      f16 hv[4];
      float hvf[4];
      #pragma unroll
      for (int q=0; q<4; ++q){
        const int kl = ckl + q;
        float gi = gsum(gS, crow, kl)    + bS[kl];
        float gf = gsum(gS, crow, 32+kl) + bS[32+kl];
        float gg = gsum(gS, crow, 64+kl) + bS[64+kl];
        float go = gsum(gS, crow, 96+kl) + bS[96+kl];
        float cc = sigm(gf)*creg[q] + sigm(gi)*tanh_(gg);
        creg[q] = cc;
        hvf[q] = sigm(go)*tanh_(cc);
        hv[q] = (f16)hvf[q];
      }
      __syncthreads();                                   // #2

      union { f16 h4[4]; u32x2 u; } pk;
      #pragma unroll
      for (int q=0; q<4; ++q) pk.h4[q] = hv[q];
      stg8_cv(h1b + (size_t)((t+1)&1)*HS_SLOT/2 + (size_t)(g*32+crow)*HN + j*32 + ckl, pk.u);

      float pp = hvf[0]*pwS[ckl] + hvf[1]*pwS[ckl+1] + hvf[2]*pwS[ckl+2] + hvf[3]*pwS[ckl+3];
      pp += __shfl_xor(pp, 1);
      pp += __shfl_xor(pp, 2);
      pp += __shfl_xor(pp, 4);
      if ((tid & 7) == 0) stg4f_cv(ypb + (size_t)(g*32+crow)*NSL + j, pp);
      post_wave2(F1g + fslot, TSN + t + 1, FD1g + fslot, t + 1);
    }
  }
}

extern "C" void kernel_launch(void* const* d_in, const int* in_sizes, int n_in,
                              void* d_out, int out_size, void* d_ws, size_t ws_size,
                              hipStream_t stream)
{
  (void)in_sizes; (void)n_in; (void)out_size; (void)ws_size;
  const float* src   = (const float*)d_in[0];
  const float* wih0e = (const float*)d_in[1];
  const float* hh0e  = (const float*)d_in[2];
  const float* b0e   = (const float*)d_in[3];
  const float* ih1e  = (const float*)d_in[4];
  const float* hh1e  = (const float*)d_in[5];
  const float* b1e   = (const float*)d_in[6];
  const float* wih0d = (const float*)d_in[7];
  const float* hh0d  = (const float*)d_in[8];
  const float* b0d   = (const float*)d_in[9];
  const float* ih1d  = (const float*)d_in[10];
  const float* hh1d  = (const float*)d_in[11];
  const float* b1d   = (const float*)d_in[12];
  const float* projw = (const float*)d_in[13];
  const float* projb = (const float*)d_in[14];
  uint8_t* ws = (uint8_t*)d_ws;
  float* out = (float*)d_out;

  k_init<<<dim3(256), dim3(256), 0, stream>>>(ws);
  k_wconv<<<dim3(6*NSL*SRN*HN/256), dim3(256), 0, stream>>>(hh0e, ih1e, hh1e, hh0d, ih1d, hh1d,
                                                            (f16*)(ws + WQ_OFF));
  k_main<<<dim3(256), dim3(256), 0, stream>>>(src, wih0e, b0e, b1e, wih0d, b0d, b1d,
                                              projw, projb, ws, out);
}